// Round 8
// baseline (213.919 us; speedup 1.0000x reference)
//
#include <hip/hip_runtime.h>
#include <stdint.h>

// InstanceHead on MI355X — f32/int32 inputs, f32 OUTPUT buffer.
// N=100000, M=256, B=8, L=128, D=64.  Batch ids UNSORTED (jnp.sort axis=-1 on
// (N,1) is a no-op).  out = (normalize(feats@W+b) @ (conf*(cen@W+b))^T) * attn.
// R8: R7 wave-autonomous structure + (1) non-temporal feats/out streams so the
// reused tables (cen 32KB, W^T 16KB, cmeta 4KB) stay L1-hot, (2) dist pass
// overlaps the in-flight HBM feats fetch, (3) HW bf16 converts (v_cvt_pk).

#define NN 100000
#define MM 256
#define LL 128
#define DD 64
#define NTILES (NN / 16)  // 6250, exact

typedef float f32x4 __attribute__((ext_vector_type(4)));
typedef __bf16 bf16x8 __attribute__((ext_vector_type(8)));

union U16x8 { uint4 u; bf16x8 v; unsigned short s[8]; };
union BU { __bf16 b; unsigned short u; };

static __device__ __forceinline__ unsigned short f2bf(float f) {
  union { float f; unsigned int i; } t; t.f = f;
  unsigned int x = t.i;
  x += 0x7fffu + ((x >> 16) & 1u);  // round-to-nearest-even
  return (unsigned short)(x >> 16);
}

// ---------------- prep: cen (bf16), W^T (bf16), centroid meta ----------------
__global__ __launch_bounds__(256) void prep_kernel(
    const int* __restrict__ cen_coords,
    const float* __restrict__ cen_feats,
    const float* __restrict__ conf,
    const float* __restrict__ W,
    const float* __restrict__ bvec,
    unsigned short* __restrict__ cen_ws,   // [256][64] bf16
    unsigned short* __restrict__ wt_ws,    // [64][128] bf16 (W transposed)
    float4* __restrict__ cmeta_ws)         // [256] {batch, x, y, z}
{
  int tid = threadIdx.x;
  if (blockIdx.x < 16) {
    int m = blockIdx.x * 16 + (tid >> 4);
    int c = tid & 15;
    float a0 = 0.f, a1 = 0.f, a2 = 0.f, a3 = 0.f;
    for (int l = 0; l < LL; l++) {
      float f = cen_feats[m * LL + l];
      const float* wr = W + l * DD + c;
      a0 += f * wr[0];  a1 += f * wr[16];
      a2 += f * wr[32]; a3 += f * wr[48];
    }
    float cf = conf[m];
    cen_ws[m * DD + c +  0] = f2bf(cf * (a0 + bvec[c +  0]));
    cen_ws[m * DD + c + 16] = f2bf(cf * (a1 + bvec[c + 16]));
    cen_ws[m * DD + c + 32] = f2bf(cf * (a2 + bvec[c + 32]));
    cen_ws[m * DD + c + 48] = f2bf(cf * (a3 + bvec[c + 48]));
  } else {
    for (int i = tid; i < LL * DD; i += 256) {
      int l = i >> 6, d = i & 63;
      wt_ws[d * LL + l] = f2bf(W[l * DD + d]);
    }
    {
      int4 cc = ((const int4*)cen_coords)[tid];  // tid < 256 == MM
      float4 f; f.x = (float)cc.x; f.y = (float)cc.y; f.z = (float)cc.z; f.w = (float)cc.w;
      cmeta_ws[tid] = f;
    }
  }
}

// ---------------- main: 1 wave per 16-row tile, one barrier ----------------
__global__ __launch_bounds__(256) void main_kernel(
    const int4* __restrict__ clu_coords4,
    const float* __restrict__ feats,
    const float* __restrict__ bvec,
    const unsigned short* __restrict__ cen_ws,
    const unsigned short* __restrict__ wt_ws,
    const float4* __restrict__ cmeta,
    float* __restrict__ out)
{
  __shared__ __align__(16) unsigned short clu_s[4][16 * 72];  // wave-private slices

  int tid = threadIdx.x;
  int wave = tid >> 6, lane = tid & 63;
  int q = lane >> 4, c = lane & 15;
  int tile = blockIdx.x * 4 + wave;
  bool live = tile < NTILES;

  float inv_nrm[4], scale[4];
  float dv[16][4];
  if (live) {
    // ---- row meta for this lane's 4 C-rows (needed by dist pass)
    int rb[4]; float rx[4], ry[4], rz[4];
#pragma unroll
    for (int r = 0; r < 4; r++) {
      int4 rm = clu_coords4[tile * 16 + q * 4 + r];
      rb[r] = rm.x; rx[r] = (float)rm.y; ry[r] = (float)rm.z; rz[r] = (float)rm.w;
    }

    // ---- issue the only HBM reads (feats) NOW, non-temporal (don't thrash L1)
    const f32x4* fb = (const f32x4*)(feats + (size_t)(tile * 16 + c) * LL);
    f32x4 f[8];
#pragma unroll
    for (int ks = 0; ks < 4; ks++) {
      f[ks * 2 + 0] = __builtin_nontemporal_load(&fb[ks * 8 + q * 2]);
      f[ks * 2 + 1] = __builtin_nontemporal_load(&fb[ks * 8 + q * 2 + 1]);
    }

    // ---- dist pass A (overlaps the in-flight feats fetch): this lane's 64
    //      dists (col = mt*16+c, row = q*4+r), once each; invalid -> 1e30.
    float dmin[4] = {1e30f, 1e30f, 1e30f, 1e30f};
#pragma unroll
    for (int mt = 0; mt < 16; mt++) {
      float4 cm = cmeta[mt * 16 + c];
      int cbatch = (int)cm.x;
#pragma unroll
      for (int r = 0; r < 4; r++) {
        float dx = rx[r] - cm.y, dy = ry[r] - cm.z, dz = rz[r] - cm.w;
        float d = fmaxf(sqrtf(dx*dx + dy*dy + dz*dz), 0.1f);
        d = (cbatch == rb[r]) ? d : 1e30f;
        dv[mt][r] = d;
        dmin[r] = fminf(dmin[r], d);
      }
    }

    // ---- GEMM1: clu = feats @ W (+b).  B-frags from W^T (now L1-hot).
    f32x4 acc[4] = {{0,0,0,0},{0,0,0,0},{0,0,0,0},{0,0,0,0}};
    const uint4* wb = (const uint4*)wt_ws;
#pragma unroll
    for (int ks = 0; ks < 4; ks++) {
      f32x4 f0 = f[ks * 2], f1 = f[ks * 2 + 1];
      U16x8 a;
      a.v = (bf16x8){(__bf16)f0[0], (__bf16)f0[1], (__bf16)f0[2], (__bf16)f0[3],
                     (__bf16)f1[0], (__bf16)f1[1], (__bf16)f1[2], (__bf16)f1[3]};
#pragma unroll
      for (int nt = 0; nt < 4; nt++) {
        U16x8 b; b.u = wb[(nt * 16 + c) * 16 + ks * 4 + q];
        acc[nt] = __builtin_amdgcn_mfma_f32_16x16x32_bf16(a.v, b.v, acc[nt], 0, 0, 0);
      }
    }
#pragma unroll
    for (int nt = 0; nt < 4; nt++) {
      float bv = bvec[nt * 16 + c];
      acc[nt][0] += bv; acc[nt][1] += bv; acc[nt][2] += bv; acc[nt][3] += bv;
    }
    // ---- row L2 norms (row r = q*4+reg lives across the 16 lanes of quad q)
#pragma unroll
    for (int r = 0; r < 4; r++) {
      float s = acc[0][r]*acc[0][r] + acc[1][r]*acc[1][r] + acc[2][r]*acc[2][r] + acc[3][r]*acc[3][r];
      s += __shfl_xor(s, 1); s += __shfl_xor(s, 2); s += __shfl_xor(s, 4); s += __shfl_xor(s, 8);
      inv_nrm[r] = 1.0f / fmaxf(sqrtf(s), 1e-12f);
    }
    // ---- clu tile -> LDS (bf16, HW cvt); norm folded into epilogue scale
#pragma unroll
    for (int nt = 0; nt < 4; nt++)
#pragma unroll
      for (int r = 0; r < 4; r++) {
        BU t; t.b = (__bf16)acc[nt][r];
        clu_s[wave][(q * 4 + r) * 72 + nt * 16 + c] = t.u;
      }

    // ---- dmin over the row's 16 lanes; clamp so empty rows output exact 0
#pragma unroll
    for (int r = 0; r < 4; r++) {
      dmin[r] = fminf(dmin[r], __shfl_xor(dmin[r], 1));
      dmin[r] = fminf(dmin[r], __shfl_xor(dmin[r], 2));
      dmin[r] = fminf(dmin[r], __shfl_xor(dmin[r], 4));
      dmin[r] = fminf(dmin[r], __shfl_xor(dmin[r], 8));
      dmin[r] = fminf(dmin[r], 1e29f);
    }
    // ---- pass B: e = exp(dmin - d) in place (invalid: arg ~ -1e30 -> 0)
    float rsum[4] = {0.f, 0.f, 0.f, 0.f};
#pragma unroll
    for (int mt = 0; mt < 16; mt++)
#pragma unroll
      for (int r = 0; r < 4; r++) {
        float e = __expf(dmin[r] - dv[mt][r]);
        dv[mt][r] = e;
        rsum[r] += e;
      }
#pragma unroll
    for (int r = 0; r < 4; r++) {
      rsum[r] += __shfl_xor(rsum[r], 1);
      rsum[r] += __shfl_xor(rsum[r], 2);
      rsum[r] += __shfl_xor(rsum[r], 4);
      rsum[r] += __shfl_xor(rsum[r], 8);
      scale[r] = (rsum[r] > 0.f) ? inv_nrm[r] / rsum[r] : 0.f;
    }
  }
  __syncthreads();  // the ONLY barrier (clu_s write -> A-frag read)
  if (!live) return;

  // ---- GEMM2 A-frags from LDS
  const uint4* cb = (const uint4*)(clu_s[wave]);
  U16x8 a0, a1;
  a0.u = cb[c * 9 + q];       // k = 0..31
  a1.u = cb[c * 9 + 4 + q];   // k = 32..63

  const uint4* cenb = (const uint4*)cen_ws;
  size_t orow = (size_t)(tile * 16) * MM;
  float* op0 = out + orow + (size_t)(q * 4 + 0) * MM;
  float* op1 = op0 + MM, *op2 = op1 + MM, *op3 = op2 + MM;
#pragma unroll
  for (int mt = 0; mt < 16; mt++) {
    U16x8 b0, b1;
    b0.u = cenb[(mt * 16 + c) * 8 + q];
    b1.u = cenb[(mt * 16 + c) * 8 + 4 + q];
    f32x4 dacc = {0, 0, 0, 0};
    dacc = __builtin_amdgcn_mfma_f32_16x16x32_bf16(a0.v, b0.v, dacc, 0, 0, 0);
    dacc = __builtin_amdgcn_mfma_f32_16x16x32_bf16(a1.v, b1.v, dacc, 0, 0, 0);
    int m = mt * 16 + c;
    __builtin_nontemporal_store(dacc[0] * dv[mt][0] * scale[0], op0 + m);
    __builtin_nontemporal_store(dacc[1] * dv[mt][1] * scale[1], op1 + m);
    __builtin_nontemporal_store(dacc[2] * dv[mt][2] * scale[2], op2 + m);
    __builtin_nontemporal_store(dacc[3] * dv[mt][3] * scale[3], op3 + m);
  }
}

extern "C" void kernel_launch(void* const* d_in, const int* in_sizes, int n_in,
                              void* d_out, int out_size, void* d_ws, size_t ws_size,
                              hipStream_t stream) {
  const int* clu_coords = (const int*)d_in[0];
  const int* cen_coords = (const int*)d_in[1];
  const float* clu_feats = (const float*)d_in[2];
  const float* cen_feats = (const float*)d_in[3];
  const float* conf      = (const float*)d_in[4];
  const float* W         = (const float*)d_in[5];
  const float* bvec      = (const float*)d_in[6];
  float* out = (float*)d_out;

  char* ws = (char*)d_ws;
  unsigned short* cen_ws = (unsigned short*)ws;              // 32768 B
  unsigned short* wt_ws  = (unsigned short*)(ws + 32768);    // 16384 B
  float4* cmeta_ws       = (float4*)(ws + 32768 + 16384);    // 4096 B

  prep_kernel<<<17, 256, 0, stream>>>(cen_coords, cen_feats, conf, W, bvec,
                                      cen_ws, wt_ws, cmeta_ws);
  main_kernel<<<(NTILES + 3) / 4, 256, 0, stream>>>(
      (const int4*)clu_coords, clu_feats, bvec, cen_ws, wt_ws, cmeta_ws, out);
}

// Round 10
// 204.437 us; speedup vs baseline: 1.0464x; 1.0464x over previous
//
#include <hip/hip_runtime.h>
#include <stdint.h>

// InstanceHead on MI355X — f32/int32 inputs, f32 OUTPUT buffer.
// N=100000, M=256, B=8, L=128, D=64.  Batch ids UNSORTED (jnp.sort axis=-1 on
// (N,1) is a no-op).  out = (normalize(feats@W+b) @ (conf*(cen@W+b))^T) * attn.
// R10 = R9 with the nontemporal-load type fixed (clang ext-vector, not HIP uint4):
//   K1 streams feats -> normalized clu in A-FRAGMENT ORDER (2KB/tile, ws)
//   K2 (no LDS, no barrier, no feats): clu frags from L3 + dist/exp + GEMM2.
// NT loads only on pure streams; normal stores (R8: NT stores amplify writes
// 100->127MB via early 128B-line eviction).

#define NN 100000
#define MM 256
#define LL 128
#define DD 64
#define NTILES (NN / 16)  // 6250, exact

typedef float f32x4 __attribute__((ext_vector_type(4)));
typedef unsigned int u32x4 __attribute__((ext_vector_type(4)));
typedef __bf16 bf16x8 __attribute__((ext_vector_type(8)));

union U16x8 { uint4 u; u32x4 e; bf16x8 v; unsigned short s[8]; };
union BU { __bf16 b; unsigned short u; };

static __device__ __forceinline__ unsigned short f2bf(float f) {
  union { float f; unsigned int i; } t; t.f = f;
  unsigned int x = t.i;
  x += 0x7fffu + ((x >> 16) & 1u);  // round-to-nearest-even
  return (unsigned short)(x >> 16);
}

// ---------------- prep: cen (bf16), W^T (bf16), centroid meta ----------------
__global__ __launch_bounds__(256) void prep_kernel(
    const int* __restrict__ cen_coords,
    const float* __restrict__ cen_feats,
    const float* __restrict__ conf,
    const float* __restrict__ W,
    const float* __restrict__ bvec,
    unsigned short* __restrict__ cen_ws,   // [256][64] bf16
    unsigned short* __restrict__ wt_ws,    // [64][128] bf16 (W transposed)
    float4* __restrict__ cmeta_ws)         // [256] {batch, x, y, z}
{
  int tid = threadIdx.x;
  if (blockIdx.x < 16) {
    int m = blockIdx.x * 16 + (tid >> 4);
    int c = tid & 15;
    float a0 = 0.f, a1 = 0.f, a2 = 0.f, a3 = 0.f;
    for (int l = 0; l < LL; l++) {
      float f = cen_feats[m * LL + l];
      const float* wr = W + l * DD + c;
      a0 += f * wr[0];  a1 += f * wr[16];
      a2 += f * wr[32]; a3 += f * wr[48];
    }
    float cf = conf[m];
    cen_ws[m * DD + c +  0] = f2bf(cf * (a0 + bvec[c +  0]));
    cen_ws[m * DD + c + 16] = f2bf(cf * (a1 + bvec[c + 16]));
    cen_ws[m * DD + c + 32] = f2bf(cf * (a2 + bvec[c + 32]));
    cen_ws[m * DD + c + 48] = f2bf(cf * (a3 + bvec[c + 48]));
  } else {
    for (int i = tid; i < LL * DD; i += 256) {
      int l = i >> 6, d = i & 63;
      wt_ws[d * LL + l] = f2bf(W[l * DD + d]);
    }
    {
      int4 cc = ((const int4*)cen_coords)[tid];  // tid < 256 == MM
      float4 f; f.x = (float)cc.x; f.y = (float)cc.y; f.z = (float)cc.z; f.w = (float)cc.w;
      cmeta_ws[tid] = f;
    }
  }
}

// ---------------- K1: feats -> normalized clu, A-fragment order ----------------
__global__ __launch_bounds__(256) void gemm1_kernel(
    const float* __restrict__ feats,
    const float* __restrict__ bvec,
    const unsigned short* __restrict__ wt_ws,
    u32x4* __restrict__ clu_ws)            // [NTILES][128] u32x4: frag0 then frag1
{
  __shared__ __align__(16) unsigned short clu_s[4][16 * 72];  // wave-private

  int tid = threadIdx.x;
  int wave = tid >> 6, lane = tid & 63;
  int q = lane >> 4, c = lane & 15;
  int tile = blockIdx.x * 4 + wave;
  bool live = tile < NTILES;

  if (live) {
    // feats: the only HBM stream — NT so the W^T table stays cache-hot
    const f32x4* fb = (const f32x4*)(feats + (size_t)(tile * 16 + c) * LL);
    f32x4 acc[4] = {{0,0,0,0},{0,0,0,0},{0,0,0,0},{0,0,0,0}};
    const uint4* wb = (const uint4*)wt_ws;
#pragma unroll
    for (int ks = 0; ks < 4; ks++) {
      f32x4 f0 = __builtin_nontemporal_load(&fb[ks * 8 + q * 2]);
      f32x4 f1 = __builtin_nontemporal_load(&fb[ks * 8 + q * 2 + 1]);
      U16x8 a;
      a.v = (bf16x8){(__bf16)f0[0], (__bf16)f0[1], (__bf16)f0[2], (__bf16)f0[3],
                     (__bf16)f1[0], (__bf16)f1[1], (__bf16)f1[2], (__bf16)f1[3]};
#pragma unroll
      for (int nt = 0; nt < 4; nt++) {
        U16x8 b; b.u = wb[(nt * 16 + c) * 16 + ks * 4 + q];
        acc[nt] = __builtin_amdgcn_mfma_f32_16x16x32_bf16(a.v, b.v, acc[nt], 0, 0, 0);
      }
    }
#pragma unroll
    for (int nt = 0; nt < 4; nt++) {
      float bv = bvec[nt * 16 + c];
      acc[nt][0] += bv; acc[nt][1] += bv; acc[nt][2] += bv; acc[nt][3] += bv;
    }
    // row L2 norms (row r = q*4+reg across the 16 lanes of quad q); fold into clu
#pragma unroll
    for (int r = 0; r < 4; r++) {
      float s = acc[0][r]*acc[0][r] + acc[1][r]*acc[1][r] + acc[2][r]*acc[2][r] + acc[3][r]*acc[3][r];
      s += __shfl_xor(s, 1); s += __shfl_xor(s, 2); s += __shfl_xor(s, 4); s += __shfl_xor(s, 8);
      float invn = 1.0f / fmaxf(sqrtf(s), 1e-12f);
      acc[0][r] *= invn; acc[1][r] *= invn; acc[2][r] *= invn; acc[3][r] *= invn;
    }
    // C-layout -> A-layout via LDS (+8/row pad: 2-way bank alias only)
#pragma unroll
    for (int nt = 0; nt < 4; nt++)
#pragma unroll
      for (int r = 0; r < 4; r++) {
        BU t; t.b = (__bf16)acc[nt][r];
        clu_s[wave][(q * 4 + r) * 72 + nt * 16 + c] = t.u;
      }
  }
  __syncthreads();
  if (!live) return;
  const u32x4* cb = (const u32x4*)(clu_s[wave]);
  u32x4 a0 = cb[c * 9 + q];       // A-frag k = 0..31
  u32x4 a1 = cb[c * 9 + 4 + q];   // A-frag k = 32..63
  // store in the exact order K2 reads: fully coalesced, L3-resident for K2
  clu_ws[(size_t)tile * 128 + lane] = a0;
  clu_ws[(size_t)tile * 128 + 64 + lane] = a1;
}

// ---------------- K2: dist/exp + GEMM2 + store.  No LDS, no barrier. ---------
__global__ __launch_bounds__(256) void main_kernel(
    const int4* __restrict__ clu_coords4,
    const u32x4* __restrict__ clu_ws,
    const unsigned short* __restrict__ cen_ws,
    const float4* __restrict__ cmeta,
    float* __restrict__ out)
{
  int tid = threadIdx.x;
  int wave = tid >> 6, lane = tid & 63;
  int q = lane >> 4, c = lane & 15;
  int tile = blockIdx.x * 4 + wave;
  if (tile >= NTILES) return;

  // ---- issue A-frag loads first (L3-resident stream, NT to spare L1)
  U16x8 a0, a1;
  a0.e = __builtin_nontemporal_load(&clu_ws[(size_t)tile * 128 + lane]);
  a1.e = __builtin_nontemporal_load(&clu_ws[(size_t)tile * 128 + 64 + lane]);

  // ---- row meta for this lane's 4 C-rows
  int rb[4]; float rx[4], ry[4], rz[4];
#pragma unroll
  for (int r = 0; r < 4; r++) {
    int4 rm = clu_coords4[tile * 16 + q * 4 + r];
    rb[r] = rm.x; rx[r] = (float)rm.y; ry[r] = (float)rm.z; rz[r] = (float)rm.w;
  }

  // ---- dist pass (overlaps the in-flight clu loads): 64 dists, once each
  float dv[16][4];
  float dmin[4] = {1e30f, 1e30f, 1e30f, 1e30f};
#pragma unroll
  for (int mt = 0; mt < 16; mt++) {
    float4 cm = cmeta[mt * 16 + c];
    int cbatch = (int)cm.x;
#pragma unroll
    for (int r = 0; r < 4; r++) {
      float dx = rx[r] - cm.y, dy = ry[r] - cm.z, dz = rz[r] - cm.w;
      float d = fmaxf(sqrtf(dx*dx + dy*dy + dz*dz), 0.1f);
      d = (cbatch == rb[r]) ? d : 1e30f;
      dv[mt][r] = d;
      dmin[r] = fminf(dmin[r], d);
    }
  }
#pragma unroll
  for (int r = 0; r < 4; r++) {
    dmin[r] = fminf(dmin[r], __shfl_xor(dmin[r], 1));
    dmin[r] = fminf(dmin[r], __shfl_xor(dmin[r], 2));
    dmin[r] = fminf(dmin[r], __shfl_xor(dmin[r], 4));
    dmin[r] = fminf(dmin[r], __shfl_xor(dmin[r], 8));
    dmin[r] = fminf(dmin[r], 1e29f);  // empty row -> exact 0 output
  }
  float rsum[4] = {0.f, 0.f, 0.f, 0.f};
#pragma unroll
  for (int mt = 0; mt < 16; mt++)
#pragma unroll
    for (int r = 0; r < 4; r++) {
      float e = __expf(dmin[r] - dv[mt][r]);   // invalid: arg ~ -1e30 -> 0
      dv[mt][r] = e;
      rsum[r] += e;
    }
  float scale[4];
#pragma unroll
  for (int r = 0; r < 4; r++) {
    rsum[r] += __shfl_xor(rsum[r], 1);
    rsum[r] += __shfl_xor(rsum[r], 2);
    rsum[r] += __shfl_xor(rsum[r], 4);
    rsum[r] += __shfl_xor(rsum[r], 8);
    scale[r] = (rsum[r] > 0.f) ? 1.f / rsum[r] : 0.f;  // inv_nrm already in clu
  }

  // ---- GEMM2 + fused epilogue (cen table is L1-hot: no stream thrashes it)
  const uint4* cenb = (const uint4*)cen_ws;
  size_t orow = (size_t)(tile * 16) * MM;
  float* op0 = out + orow + (size_t)(q * 4 + 0) * MM;
  float* op1 = op0 + MM, *op2 = op1 + MM, *op3 = op2 + MM;
#pragma unroll
  for (int mt = 0; mt < 16; mt++) {
    U16x8 b0, b1;
    b0.u = cenb[(mt * 16 + c) * 8 + q];
    b1.u = cenb[(mt * 16 + c) * 8 + 4 + q];
    f32x4 dacc = {0, 0, 0, 0};
    dacc = __builtin_amdgcn_mfma_f32_16x16x32_bf16(a0.v, b0.v, dacc, 0, 0, 0);
    dacc = __builtin_amdgcn_mfma_f32_16x16x32_bf16(a1.v, b1.v, dacc, 0, 0, 0);
    int m = mt * 16 + c;
    op0[m] = dacc[0] * dv[mt][0] * scale[0];
    op1[m] = dacc[1] * dv[mt][1] * scale[1];
    op2[m] = dacc[2] * dv[mt][2] * scale[2];
    op3[m] = dacc[3] * dv[mt][3] * scale[3];
  }
}

extern "C" void kernel_launch(void* const* d_in, const int* in_sizes, int n_in,
                              void* d_out, int out_size, void* d_ws, size_t ws_size,
                              hipStream_t stream) {
  const int* clu_coords = (const int*)d_in[0];
  const int* cen_coords = (const int*)d_in[1];
  const float* clu_feats = (const float*)d_in[2];
  const float* cen_feats = (const float*)d_in[3];
  const float* conf      = (const float*)d_in[4];
  const float* W         = (const float*)d_in[5];
  const float* bvec      = (const float*)d_in[6];
  float* out = (float*)d_out;

  char* ws = (char*)d_ws;
  unsigned short* cen_ws = (unsigned short*)ws;              // 32768 B
  unsigned short* wt_ws  = (unsigned short*)(ws + 32768);    // 16384 B
  float4* cmeta_ws       = (float4*)(ws + 32768 + 16384);    // 4096 B
  u32x4* clu_ws          = (u32x4*)(ws + 65536);             // 12.8 MB (NTILES*2KB)

  prep_kernel<<<17, 256, 0, stream>>>(cen_coords, cen_feats, conf, W, bvec,
                                      cen_ws, wt_ws, cmeta_ws);
  gemm1_kernel<<<(NTILES + 3) / 4, 256, 0, stream>>>(
      clu_feats, bvec, wt_ws, clu_ws);
  main_kernel<<<(NTILES + 3) / 4, 256, 0, stream>>>(
      (const int4*)clu_coords, clu_ws, cen_ws, cmeta_ws, out);
}